// Round 9
// baseline (199.960 us; speedup 1.0000x reference)
//
#include <hip/hip_runtime.h>
#include <hip/hip_bf16.h>
#include <math.h>

#define NPOS   1024
#define NSAMP  16
#define DMODEL 256
#define DINNER 512
#define DSTATE 16
#define DTRANK 16
#define MROWS  (NPOS*NSAMP)   // 16384, m = s*1024 + p
#define LOG2E  1.44269504f

typedef __attribute__((ext_vector_type(8))) short short8;
typedef __attribute__((ext_vector_type(4))) float f32x4;

__device__ __forceinline__ unsigned short f2bf(float f) {
    unsigned int u = __builtin_bit_cast(unsigned int, f);
    u = u + 0x7FFFu + ((u >> 16) & 1u);
    return (unsigned short)(u >> 16);
}
__device__ __forceinline__ float bf2f(short b) {
    unsigned int u = ((unsigned int)(unsigned short)b) << 16;
    return __builtin_bit_cast(float, u);
}
__device__ __forceinline__ void unpk(unsigned int v, float& a, float& b) {
    a = __builtin_bit_cast(float, v << 16);
    b = __builtin_bit_cast(float, v & 0xffff0000u);
}
__device__ __forceinline__ float fsilu(float x) {
    return x * __builtin_amdgcn_rcpf(1.f + __expf(-x));
}
__device__ __forceinline__ void gl16(const void* g, void* l) {
    __builtin_amdgcn_global_load_lds((const __attribute__((address_space(1))) void*)g,
                                     (__attribute__((address_space(3))) void*)l, 16, 0, 0);
}

// ---------------- kprep2: knorm + coalesced weight transposes + scan constants ---
// blocks: [0,256) knorm; [256,320) w_in T; [320,352) w_out T; [352,448) wxT; 448 scanc.
__global__ __launch_bounds__(256) void kprep2(const float* __restrict__ feat,
                                              const float* __restrict__ norm_w,
                                              const float* __restrict__ w_in,
                                              const float* __restrict__ w_out,
                                              const float* __restrict__ w_xproj,
                                              const float* __restrict__ A_log,
                                              unsigned short* __restrict__ xnT,
                                              unsigned short* __restrict__ w_inT,
                                              unsigned short* __restrict__ w_outT,
                                              unsigned short* __restrict__ wxT,
                                              float2* __restrict__ scanc) {
    __shared__ float part[4][64];
    __shared__ float ssc[64];
    __shared__ char shmem[64 * 520];
    int b = blockIdx.x, t = threadIdx.x;
    if (b < 256) {
        int s = b & 15, p0 = (b >> 4) * 64;
        int pl = t & 63, cg = t >> 6;
        const float* base = feat + (size_t)s * (DMODEL * NPOS) + p0 + pl;
        float vals[64];
        float ss = 0.f;
        #pragma unroll
        for (int j = 0; j < 64; ++j) {
            float v = base[(size_t)(cg * 64 + j) * NPOS];
            vals[j] = v;
            ss += v * v;
        }
        part[cg][pl] = ss;
        __syncthreads();
        if (t < 64) {
            float tot = part[0][t] + part[1][t] + part[2][t] + part[3][t];
            ssc[t] = rsqrtf(tot * (1.f / DMODEL) + 1e-5f);
        }
        __syncthreads();
        float sc = ssc[pl];
        unsigned short* trow = (unsigned short*)(shmem + pl * 520);
        #pragma unroll
        for (int j = 0; j < 64; ++j)
            trow[cg * 64 + j] = f2bf(vals[j] * sc * norm_w[cg * 64 + j]);
        __syncthreads();
        int p = t >> 2, cb = (t & 3) * 64;
        const unsigned short* srow = (const unsigned short*)(shmem + p * 520);
        unsigned short* orow = xnT + (size_t)((s << 10) + p0 + p) * DMODEL + cb;
        #pragma unroll
        for (int j8 = 0; j8 < 8; ++j8) {
            short8 v;
            #pragma unroll
            for (int jj = 0; jj < 8; ++jj) v[jj] = srow[cb + j8 * 8 + jj];
            *reinterpret_cast<short8*>(orow + j8 * 8) = v;
        }
    } else if (b < 352) {
        const float* src; unsigned short* dst; int K, N, tk, tn;
        if (b < 320) { int tb = b - 256; src = w_in;  dst = w_inT;  K = 256; N = 1024; tk = tb >> 4; tn = tb & 15; }
        else         { int tb = b - 320; src = w_out; dst = w_outT; K = 512; N = 256;  tk = tb >> 2; tn = tb & 3;  }
        unsigned short (*tile)[65] = (unsigned short (*)[65])shmem;
        #pragma unroll
        for (int j = 0; j < 16; ++j) {
            int kl = j * 4 + (t >> 6), nl = t & 63;
            tile[kl][nl] = f2bf(src[(size_t)(tk * 64 + kl) * N + tn * 64 + nl]);
        }
        __syncthreads();
        #pragma unroll
        for (int j = 0; j < 16; ++j) {
            int nl = j * 4 + (t >> 6), kl = t & 63;
            dst[(size_t)(tn * 64 + nl) * K + tk * 64 + kl] = tile[kl][nl];
        }
    } else if (b < 448) {
        int idx = (b - 352) * 256 + t;          // 24576 = 48*512
        int j = idx >> 9, k = idx & 511;
        wxT[idx] = f2bf(w_xproj[(size_t)k * 48 + j]);
    } else {
        #pragma unroll
        for (int dd = 0; dd < 2; ++dd) {
            int d = t + dd * 256;
            float Ar0 = -__expf(A_log[d * DSTATE]);
            bool geo = true;
            #pragma unroll
            for (int n = 1; n < DSTATE; ++n) {
                float An = -__expf(A_log[d * DSTATE + n]);
                geo = geo && (fabsf(An - (n + 1) * Ar0) <= 1e-4f * (n + 1));
            }
            scanc[d] = make_float2(LOG2E * Ar0, geo ? 1.f : 0.f);
        }
    }
}

// ---------------- K1: [xm|res] = xn @ w_in, 256x128 tile, 512 thr, gl16 ---------
__global__ __launch_bounds__(512) void k1_mfma(const unsigned short* __restrict__ xnT,
                                               const unsigned short* __restrict__ w_inT,
                                               unsigned short* __restrict__ xmbf,
                                               unsigned short* __restrict__ gbf) {
    __shared__ char As[256 * 128];
    __shared__ char Bs[128 * 128];
    int t = threadIdx.x;
    int m0 = blockIdx.y * 256, n0 = blockIdx.x * 128;
    int l = t & 63, w = t >> 6;
    int wm = w & 3, wn = w >> 2, g = l >> 4, lr = l & 15;

    f32x4 acc[4][4] = {};
    for (int k0 = 0; k0 < DMODEL; k0 += 64) {
        if (k0) __syncthreads();
        #pragma unroll
        for (int q = 0; q < 4; ++q) {
            int c = q * 512 + t;
            gl16(xnT + (size_t)(m0 + (c >> 3)) * DMODEL + k0 + (c & 7) * 8, As + c * 16);
        }
        #pragma unroll
        for (int q = 0; q < 2; ++q) {
            int c = q * 512 + t;
            gl16(w_inT + (size_t)(n0 + (c >> 3)) * DMODEL + k0 + (c & 7) * 8, Bs + c * 16);
        }
        __syncthreads();
        #pragma unroll
        for (int ks = 0; ks < 2; ++ks) {
            short8 a[4], b[4];
            #pragma unroll
            for (int mi = 0; mi < 4; ++mi)
                a[mi] = *reinterpret_cast<short8*>(As + (wm * 64 + mi * 16 + lr) * 128 + ks * 64 + g * 16);
            #pragma unroll
            for (int ni = 0; ni < 4; ++ni)
                b[ni] = *reinterpret_cast<short8*>(Bs + (wn * 64 + ni * 16 + lr) * 128 + ks * 64 + g * 16);
            #pragma unroll
            for (int mi = 0; mi < 4; ++mi)
                #pragma unroll
                for (int ni = 0; ni < 4; ++ni)
                    acc[mi][ni] = __builtin_amdgcn_mfma_f32_16x16x32_bf16(a[mi], b[ni], acc[mi][ni], 0, 0, 0);
        }
    }
    bool isRes = (n0 >= 512);
    #pragma unroll
    for (int mi = 0; mi < 4; ++mi) {
        #pragma unroll
        for (int r = 0; r < 4; ++r) {
            int m = m0 + wm * 64 + mi * 16 + g * 4 + r;
            #pragma unroll
            for (int ni = 0; ni < 4; ++ni) {
                int n = n0 + wn * 64 + ni * 16 + lr;
                float v = acc[mi][ni][r];
                if (isRes) gbf[(size_t)m * DINNER + n - 512] = f2bf(fsilu(v));
                else       xmbf[(size_t)m * DINNER + n] = f2bf(v);
            }
        }
    }
}

// ---------------- K3: dbc[m][48] = silu(conv(xm)) @ w_xproj; writes u too -------
__global__ __launch_bounds__(256) void k3_mfma(const unsigned short* __restrict__ xmbf,
                                               const float* __restrict__ conv_w,
                                               const float* __restrict__ conv_b,
                                               const unsigned short* __restrict__ wxT,
                                               float* __restrict__ dbc,
                                               unsigned short* __restrict__ ubf) {
    __shared__ char Ws[48 * 128];
    __shared__ char Xs[64 * 128];
    int t = threadIdx.x;
    int m0 = blockIdx.x * 64;
    int s = m0 >> 10;
    int l = t & 63, w = t >> 6, g = l >> 4, lr = l & 15;
    f32x4 acc[3] = {};
    for (int k0 = 0; k0 < DINNER; k0 += 64) {
        if (k0) __syncthreads();
        for (int c = t; c < 384; c += 256)
            gl16(wxT + (size_t)(c >> 3) * DINNER + k0 + (c & 7) * 8, Ws + c * 16);
        #pragma unroll
        for (int q = 0; q < 2; ++q) {
            int c = q * 256 + t;
            int row = c >> 3, cb = c & 7;
            int m = m0 + row, d0 = k0 + cb * 8;
            const unsigned short* r0 = xmbf + (size_t)m * DINNER + d0;
            short8 x0 = *reinterpret_cast<const short8*>(r0);
            short8 x1 = {}, x2 = {};
            if (s >= 1) x1 = *reinterpret_cast<const short8*>(r0 - 1024 * DINNER);
            if (s >= 2) x2 = *reinterpret_cast<const short8*>(r0 - 2048 * DINNER);
            float wv[24], cb8[8];
            #pragma unroll
            for (int qq = 0; qq < 6; ++qq)
                *reinterpret_cast<float4*>(&wv[qq * 4]) = *reinterpret_cast<const float4*>(conv_w + d0 * 3 + qq * 4);
            *reinterpret_cast<float4*>(&cb8[0]) = *reinterpret_cast<const float4*>(conv_b + d0);
            *reinterpret_cast<float4*>(&cb8[4]) = *reinterpret_cast<const float4*>(conv_b + d0 + 4);
            short8 v;
            #pragma unroll
            for (int j = 0; j < 8; ++j) {
                float cv = cb8[j] + wv[3 * j + 2] * bf2f(x0[j]) + wv[3 * j + 1] * bf2f(x1[j]) + wv[3 * j] * bf2f(x2[j]);
                v[j] = (short)f2bf(fsilu(cv));
            }
            *reinterpret_cast<short8*>(Xs + c * 16) = v;
            *reinterpret_cast<short8*>(ubf + (size_t)m * DINNER + d0) = v;
        }
        __syncthreads();
        #pragma unroll
        for (int ks = 0; ks < 2; ++ks) {
            short8 bfr = *reinterpret_cast<short8*>(Xs + (w * 16 + lr) * 128 + ks * 64 + g * 16);
            #pragma unroll
            for (int aj = 0; aj < 3; ++aj) {
                short8 a = *reinterpret_cast<short8*>(Ws + (aj * 16 + lr) * 128 + ks * 64 + g * 16);
                acc[aj] = __builtin_amdgcn_mfma_f32_16x16x32_bf16(a, bfr, acc[aj], 0, 0, 0);
            }
        }
    }
    int mc = m0 + w * 16 + lr;
    #pragma unroll
    for (int aj = 0; aj < 3; ++aj)
        *reinterpret_cast<f32x4*>(dbc + (size_t)mc * 48 + aj * 16 + g * 4) = acc[aj];
}

// ---------------- K5: scan with inline delta (prefetch-time), 2 d/thread --------
__global__ __launch_bounds__(256) void k5_scan(const unsigned int* __restrict__ ubf2,
                                               const unsigned int* __restrict__ gbf2,
                                               const float* __restrict__ dbc,
                                               const float2* __restrict__ scanc,
                                               const float* __restrict__ w_dt,
                                               const float* __restrict__ b_dt,
                                               const float* __restrict__ A_log,
                                               const float* __restrict__ Dp,
                                               unsigned int* __restrict__ ybf2) {
    int p = blockIdx.x, t = threadIdx.x;
    int d0 = 2 * t, d1 = d0 + 1;
    float2 s0c = scanc[d0], s1c = scanc[d1];
    float c00 = s0c.x, c01 = s1c.x;
    bool geo = (s0c.y > 0.5f) && (s1c.y > 0.5f);
    float2 Dv = *reinterpret_cast<const float2*>(Dp + d0);
    float2 bdt = *reinterpret_cast<const float2*>(b_dt + d0);
    float wdt0[16], wdt1[16];
    #pragma unroll
    for (int r = 0; r < 16; ++r) {
        float2 wv = *reinterpret_cast<const float2*>(w_dt + r * DINNER + d0);
        wdt0[r] = wv.x; wdt1[r] = wv.y;
    }
    float h0[16], h1[16];
    #pragma unroll
    for (int n = 0; n < 16; ++n) { h0[n] = 0.f; h1[n] = 0.f; }
    unsigned int base = p * 256 + t;
    float bcA[32], bcB[32];
    unsigned int uA, gA, uB, gB;
    float dA0, dA1, dB0, dB1;

#define LOADBC(BUF, DL0, DL1, S) { \
    const float* rp = dbc + (size_t)((((S) << 10) + p) * 48); \
    float t0[16]; \
    _Pragma("unroll") for (int j = 0; j < 4; ++j) *reinterpret_cast<float4*>(&t0[j * 4]) = *reinterpret_cast<const float4*>(rp + j * 4); \
    _Pragma("unroll") for (int j = 0; j < 8; ++j) *reinterpret_cast<float4*>(&BUF[j * 4]) = *reinterpret_cast<const float4*>(rp + 16 + j * 4); \
    float dp0 = bdt.x, dp1 = bdt.y; \
    _Pragma("unroll") for (int r = 0; r < 16; ++r) { dp0 += t0[r] * wdt0[r]; dp1 += t0[r] * wdt1[r]; } \
    DL0 = (dp0 > 20.f) ? dp0 : __logf(1.f + __expf(dp0)); \
    DL1 = (dp1 > 20.f) ? dp1 : __logf(1.f + __expf(dp1)); }
#define LOADPF(U, G, S) { unsigned int o = ((unsigned int)(S) << 18) + base; U = ubf2[o]; G = gbf2[o]; }
#define STEP(S, BC, U, G, DL0, DL1) { \
    float u0, u1, g0, g1; unpk(U, u0, u1); unpk(G, g0, g1); \
    float du0 = DL0 * u0, du1 = DL1 * u1; float yv0 = 0.f, yv1 = 0.f; \
    if (geo) { \
        float r0 = exp2f(DL0 * c00), r1 = exp2f(DL1 * c01); \
        float rr0 = r0, rr1 = r1; \
        _Pragma("unroll") for (int n = 0; n < 16; ++n) { \
            h0[n] = rr0 * h0[n] + du0 * BC[n]; yv0 += h0[n] * BC[16 + n]; rr0 *= r0; \
            h1[n] = rr1 * h1[n] + du1 * BC[n]; yv1 += h1[n] * BC[16 + n]; rr1 *= r1; } \
    } else { \
        _Pragma("unroll") for (int n = 0; n < 16; ++n) { \
            float An0 = -__expf(A_log[d0 * 16 + n]); float An1 = -__expf(A_log[d1 * 16 + n]); \
            h0[n] = __expf(DL0 * An0) * h0[n] + du0 * BC[n]; yv0 += h0[n] * BC[16 + n]; \
            h1[n] = __expf(DL1 * An1) * h1[n] + du1 * BC[n]; yv1 += h1[n] * BC[16 + n]; } \
    } \
    unsigned int o = ((unsigned int)(S) << 18) + base; \
    ybf2[o] = ((unsigned int)f2bf((yv1 + u1 * Dv.y) * g1) << 16) | f2bf((yv0 + u0 * Dv.x) * g0); }

    LOADBC(bcA, dA0, dA1, 0); LOADPF(uA, gA, 0);
    #pragma unroll
    for (int it = 0; it < 8; ++it) {
        int sa = 2 * it, sb = 2 * it + 1;
        int sn = (2 * it + 2 < 16) ? 2 * it + 2 : 15;
        LOADBC(bcB, dB0, dB1, sb); LOADPF(uB, gB, sb);
        STEP(sa, bcA, uA, gA, dA0, dA1);
        LOADBC(bcA, dA0, dA1, sn); LOADPF(uA, gA, sn);
        STEP(sb, bcB, uB, gB, dB0, dB1);
    }
#undef LOADBC
#undef LOADPF
#undef STEP
}

// ---------------- K6: out = y @ w_out + x, gl16 staging, BK=64 ------------------
__global__ __launch_bounds__(256) void k6_mfma(const unsigned short* __restrict__ ybf,
                                               const unsigned short* __restrict__ w_outT,
                                               const float* __restrict__ feat,
                                               float* __restrict__ out) {
    __shared__ char As[128 * 128];   // w_outT c-tile
    __shared__ char Bs[128 * 128];   // ybf m-tile
    int t = threadIdx.x;
    int m0 = blockIdx.x * 128;
    int cblk = blockIdx.y * 128;
    int s = m0 >> 10, p0 = m0 & 1023;
    int l = t & 63, w = t >> 6;
    int wm = w & 1, wn = w >> 1, g = l >> 4, lr = l & 15;

    f32x4 acc[4][4] = {};
    for (int k0 = 0; k0 < DINNER; k0 += 64) {
        if (k0) __syncthreads();
        #pragma unroll
        for (int q = 0; q < 4; ++q) {
            int chunk = q * 256 + t;
            int row = chunk >> 3, cb = chunk & 7;
            gl16(w_outT + (size_t)(cblk + row) * DINNER + k0 + cb * 8, As + chunk * 16);
            gl16(ybf    + (size_t)(m0 + row) * DINNER + k0 + cb * 8, Bs + chunk * 16);
        }
        __syncthreads();
        #pragma unroll
        for (int ks = 0; ks < 2; ++ks) {
            short8 a[4], b[4];
            #pragma unroll
            for (int mi = 0; mi < 4; ++mi)
                a[mi] = *reinterpret_cast<short8*>(As + (wm * 64 + mi * 16 + lr) * 128 + ks * 64 + g * 16);
            #pragma unroll
            for (int ni = 0; ni < 4; ++ni)
                b[ni] = *reinterpret_cast<short8*>(Bs + (wn * 64 + ni * 16 + lr) * 128 + ks * 64 + g * 16);
            #pragma unroll
            for (int mi = 0; mi < 4; ++mi)
                #pragma unroll
                for (int ni = 0; ni < 4; ++ni)
                    acc[mi][ni] = __builtin_amdgcn_mfma_f32_16x16x32_bf16(a[mi], b[ni], acc[mi][ni], 0, 0, 0);
        }
    }
    #pragma unroll
    for (int mi = 0; mi < 4; ++mi) {
        #pragma unroll
        for (int r = 0; r < 4; ++r) {
            int c = cblk + wm * 64 + mi * 16 + g * 4 + r;
            #pragma unroll
            for (int ni = 0; ni < 4; ++ni) {
                int p = p0 + wn * 64 + ni * 16 + lr;
                size_t idx = (size_t)s * (DMODEL * NPOS) + (size_t)c * NPOS + p;
                out[idx] = acc[mi][ni][r] + feat[idx];
            }
        }
    }
}

extern "C" void kernel_launch(void* const* d_in, const int* in_sizes, int n_in,
                              void* d_out, int out_size, void* d_ws, size_t ws_size,
                              hipStream_t stream) {
    const float* feature = (const float*)d_in[0];
    const float* norm_w  = (const float*)d_in[1];
    const float* w_in    = (const float*)d_in[2];
    const float* conv_w  = (const float*)d_in[3];
    const float* conv_b  = (const float*)d_in[4];
    const float* w_xproj = (const float*)d_in[5];
    const float* w_dt    = (const float*)d_in[6];
    const float* b_dt    = (const float*)d_in[7];
    const float* A_log   = (const float*)d_in[8];
    const float* Dp      = (const float*)d_in[9];
    const float* w_out   = (const float*)d_in[10];
    float* out = (float*)d_out;

    char* ws = (char*)d_ws;
    unsigned short* xnT    = (unsigned short*)(ws + 0);         // 8.4 MB
    unsigned short* xmbf   = (unsigned short*)(ws + 8388608);   // 16.8 MB
    unsigned short* gbf    = (unsigned short*)(ws + 25165824);  // 16.8 MB
    float*          dbc    = (float*)(ws + 41943040);           // 3.1 MB
    unsigned short* ubf    = (unsigned short*)(ws + 45088768);  // 16.8 MB
    unsigned short* ybf    = (unsigned short*)(ws + 61865984);  // 16.8 MB
    unsigned short* w_inT  = (unsigned short*)(ws + 78643200);  // 512 KB
    unsigned short* w_outT = (unsigned short*)(ws + 79167488);  // 256 KB
    unsigned short* wxT    = (unsigned short*)(ws + 79429632);  // 48 KB
    float2*         scanc  = (float2*)(ws + 79478784);          // 4 KB

    kprep2<<<449, 256, 0, stream>>>(feature, norm_w, w_in, w_out, w_xproj, A_log,
                                    xnT, w_inT, w_outT, wxT, scanc);
    k1_mfma<<<dim3(1024 / 128, MROWS / 256), 512, 0, stream>>>(xnT, w_inT, xmbf, gbf);
    k3_mfma<<<MROWS / 64, 256, 0, stream>>>(xmbf, conv_w, conv_b, wxT, dbc, ubf);
    k5_scan<<<NPOS, 256, 0, stream>>>((const unsigned int*)ubf, (const unsigned int*)gbf,
                                      dbc, scanc, w_dt, b_dt, A_log, Dp, (unsigned int*)ybf);
    k6_mfma<<<dim3(MROWS / 128, DMODEL / 128), 256, 0, stream>>>(ybf, w_outT, feature, out);
}

// Round 10
// 173.214 us; speedup vs baseline: 1.1544x; 1.1544x over previous
//
#include <hip/hip_runtime.h>
#include <hip/hip_bf16.h>
#include <math.h>

#define NPOS   1024
#define NSAMP  16
#define DMODEL 256
#define DINNER 512
#define DSTATE 16
#define DTRANK 16
#define MROWS  (NPOS*NSAMP)   // 16384, m = s*1024 + p
#define LOG2E  1.44269504f

typedef __attribute__((ext_vector_type(8))) short short8;
typedef __attribute__((ext_vector_type(4))) float f32x4;

__device__ __forceinline__ unsigned short f2bf(float f) {
    unsigned int u = __builtin_bit_cast(unsigned int, f);
    u = u + 0x7FFFu + ((u >> 16) & 1u);
    return (unsigned short)(u >> 16);
}
__device__ __forceinline__ float bf2f(short b) {
    unsigned int u = ((unsigned int)(unsigned short)b) << 16;
    return __builtin_bit_cast(float, u);
}
__device__ __forceinline__ void unpk(unsigned int v, float& a, float& b) {
    a = __builtin_bit_cast(float, v << 16);
    b = __builtin_bit_cast(float, v & 0xffff0000u);
}
__device__ __forceinline__ float fsilu(float x) {
    return x * __builtin_amdgcn_rcpf(1.f + __expf(-x));
}
__device__ __forceinline__ void gl16(const void* g, void* l) {
    __builtin_amdgcn_global_load_lds((const __attribute__((address_space(1))) void*)g,
                                     (__attribute__((address_space(3))) void*)l, 16, 0, 0);
}

// ---------------- kprep2: knorm + coalesced weight transposes + scan constants ---
__global__ __launch_bounds__(256) void kprep2(const float* __restrict__ feat,
                                              const float* __restrict__ norm_w,
                                              const float* __restrict__ w_in,
                                              const float* __restrict__ w_out,
                                              const float* __restrict__ w_xproj,
                                              const float* __restrict__ A_log,
                                              unsigned short* __restrict__ xnT,
                                              unsigned short* __restrict__ w_inT,
                                              unsigned short* __restrict__ w_outT,
                                              unsigned short* __restrict__ wxT,
                                              float2* __restrict__ scanc) {
    __shared__ float part[4][64];
    __shared__ float ssc[64];
    __shared__ char shmem[64 * 520];
    int b = blockIdx.x, t = threadIdx.x;
    if (b < 256) {
        int s = b & 15, p0 = (b >> 4) * 64;
        int pl = t & 63, cg = t >> 6;
        const float* base = feat + (size_t)s * (DMODEL * NPOS) + p0 + pl;
        float vals[64];
        float ss = 0.f;
        #pragma unroll
        for (int j = 0; j < 64; ++j) {
            float v = base[(size_t)(cg * 64 + j) * NPOS];
            vals[j] = v;
            ss += v * v;
        }
        part[cg][pl] = ss;
        __syncthreads();
        if (t < 64) {
            float tot = part[0][t] + part[1][t] + part[2][t] + part[3][t];
            ssc[t] = rsqrtf(tot * (1.f / DMODEL) + 1e-5f);
        }
        __syncthreads();
        float sc = ssc[pl];
        unsigned short* trow = (unsigned short*)(shmem + pl * 520);
        #pragma unroll
        for (int j = 0; j < 64; ++j)
            trow[cg * 64 + j] = f2bf(vals[j] * sc * norm_w[cg * 64 + j]);
        __syncthreads();
        int p = t >> 2, cb = (t & 3) * 64;
        const unsigned short* srow = (const unsigned short*)(shmem + p * 520);
        unsigned short* orow = xnT + (size_t)((s << 10) + p0 + p) * DMODEL + cb;
        #pragma unroll
        for (int j8 = 0; j8 < 8; ++j8) {
            short8 v;
            #pragma unroll
            for (int jj = 0; jj < 8; ++jj) v[jj] = srow[cb + j8 * 8 + jj];
            *reinterpret_cast<short8*>(orow + j8 * 8) = v;
        }
    } else if (b < 352) {
        const float* src; unsigned short* dst; int K, N, tk, tn;
        if (b < 320) { int tb = b - 256; src = w_in;  dst = w_inT;  K = 256; N = 1024; tk = tb >> 4; tn = tb & 15; }
        else         { int tb = b - 320; src = w_out; dst = w_outT; K = 512; N = 256;  tk = tb >> 2; tn = tb & 3;  }
        unsigned short (*tile)[65] = (unsigned short (*)[65])shmem;
        #pragma unroll
        for (int j = 0; j < 16; ++j) {
            int kl = j * 4 + (t >> 6), nl = t & 63;
            tile[kl][nl] = f2bf(src[(size_t)(tk * 64 + kl) * N + tn * 64 + nl]);
        }
        __syncthreads();
        #pragma unroll
        for (int j = 0; j < 16; ++j) {
            int nl = j * 4 + (t >> 6), kl = t & 63;
            dst[(size_t)(tn * 64 + nl) * K + tk * 64 + kl] = tile[kl][nl];
        }
    } else if (b < 448) {
        int idx = (b - 352) * 256 + t;          // 24576 = 48*512
        int j = idx >> 9, k = idx & 511;
        wxT[idx] = f2bf(w_xproj[(size_t)k * 48 + j]);
    } else {
        #pragma unroll
        for (int dd = 0; dd < 2; ++dd) {
            int d = t + dd * 256;
            float Ar0 = -__expf(A_log[d * DSTATE]);
            bool geo = true;
            #pragma unroll
            for (int n = 1; n < DSTATE; ++n) {
                float An = -__expf(A_log[d * DSTATE + n]);
                geo = geo && (fabsf(An - (n + 1) * Ar0) <= 1e-4f * (n + 1));
            }
            scanc[d] = make_float2(LOG2E * Ar0, geo ? 1.f : 0.f);
        }
    }
}

// ---------------- K1: [xm|res] = xn @ w_in, 256x128 tile, 512 thr, gl16 ---------
__global__ __launch_bounds__(512) void k1_mfma(const unsigned short* __restrict__ xnT,
                                               const unsigned short* __restrict__ w_inT,
                                               unsigned short* __restrict__ xmbf,
                                               unsigned short* __restrict__ gbf) {
    __shared__ char As[256 * 128];
    __shared__ char Bs[128 * 128];
    int t = threadIdx.x;
    int m0 = blockIdx.y * 256, n0 = blockIdx.x * 128;
    int l = t & 63, w = t >> 6;
    int wm = w & 3, wn = w >> 2, g = l >> 4, lr = l & 15;

    f32x4 acc[4][4] = {};
    for (int k0 = 0; k0 < DMODEL; k0 += 64) {
        if (k0) __syncthreads();
        #pragma unroll
        for (int q = 0; q < 4; ++q) {
            int c = q * 512 + t;
            gl16(xnT + (size_t)(m0 + (c >> 3)) * DMODEL + k0 + (c & 7) * 8, As + c * 16);
        }
        #pragma unroll
        for (int q = 0; q < 2; ++q) {
            int c = q * 512 + t;
            gl16(w_inT + (size_t)(n0 + (c >> 3)) * DMODEL + k0 + (c & 7) * 8, Bs + c * 16);
        }
        __syncthreads();
        #pragma unroll
        for (int ks = 0; ks < 2; ++ks) {
            short8 a[4], b[4];
            #pragma unroll
            for (int mi = 0; mi < 4; ++mi)
                a[mi] = *reinterpret_cast<short8*>(As + (wm * 64 + mi * 16 + lr) * 128 + ks * 64 + g * 16);
            #pragma unroll
            for (int ni = 0; ni < 4; ++ni)
                b[ni] = *reinterpret_cast<short8*>(Bs + (wn * 64 + ni * 16 + lr) * 128 + ks * 64 + g * 16);
            #pragma unroll
            for (int mi = 0; mi < 4; ++mi)
                #pragma unroll
                for (int ni = 0; ni < 4; ++ni)
                    acc[mi][ni] = __builtin_amdgcn_mfma_f32_16x16x32_bf16(a[mi], b[ni], acc[mi][ni], 0, 0, 0);
        }
    }
    bool isRes = (n0 >= 512);
    #pragma unroll
    for (int mi = 0; mi < 4; ++mi) {
        #pragma unroll
        for (int r = 0; r < 4; ++r) {
            int m = m0 + wm * 64 + mi * 16 + g * 4 + r;
            #pragma unroll
            for (int ni = 0; ni < 4; ++ni) {
                int n = n0 + wn * 64 + ni * 16 + lr;
                float v = acc[mi][ni][r];
                if (isRes) gbf[(size_t)m * DINNER + n - 512] = f2bf(fsilu(v));
                else       xmbf[(size_t)m * DINNER + n] = f2bf(v);
            }
        }
    }
}

// ---------------- K3: dbc[m][48] = silu(conv(xm)) @ w_xproj; writes u too -------
__global__ __launch_bounds__(256) void k3_mfma(const unsigned short* __restrict__ xmbf,
                                               const float* __restrict__ conv_w,
                                               const float* __restrict__ conv_b,
                                               const unsigned short* __restrict__ wxT,
                                               float* __restrict__ dbc,
                                               unsigned short* __restrict__ ubf) {
    __shared__ char Ws[48 * 128];
    __shared__ char Xs[64 * 128];
    int t = threadIdx.x;
    int m0 = blockIdx.x * 64;
    int s = m0 >> 10;
    int l = t & 63, w = t >> 6, g = l >> 4, lr = l & 15;
    f32x4 acc[3] = {};
    for (int k0 = 0; k0 < DINNER; k0 += 64) {
        if (k0) __syncthreads();
        for (int c = t; c < 384; c += 256)
            gl16(wxT + (size_t)(c >> 3) * DINNER + k0 + (c & 7) * 8, Ws + c * 16);
        #pragma unroll
        for (int q = 0; q < 2; ++q) {
            int c = q * 256 + t;
            int row = c >> 3, cb = c & 7;
            int m = m0 + row, d0 = k0 + cb * 8;
            const unsigned short* r0 = xmbf + (size_t)m * DINNER + d0;
            short8 x0 = *reinterpret_cast<const short8*>(r0);
            short8 x1 = {}, x2 = {};
            if (s >= 1) x1 = *reinterpret_cast<const short8*>(r0 - 1024 * DINNER);
            if (s >= 2) x2 = *reinterpret_cast<const short8*>(r0 - 2048 * DINNER);
            float wv[24], cb8[8];
            #pragma unroll
            for (int qq = 0; qq < 6; ++qq)
                *reinterpret_cast<float4*>(&wv[qq * 4]) = *reinterpret_cast<const float4*>(conv_w + d0 * 3 + qq * 4);
            *reinterpret_cast<float4*>(&cb8[0]) = *reinterpret_cast<const float4*>(conv_b + d0);
            *reinterpret_cast<float4*>(&cb8[4]) = *reinterpret_cast<const float4*>(conv_b + d0 + 4);
            short8 v;
            #pragma unroll
            for (int j = 0; j < 8; ++j) {
                float cv = cb8[j] + wv[3 * j + 2] * bf2f(x0[j]) + wv[3 * j + 1] * bf2f(x1[j]) + wv[3 * j] * bf2f(x2[j]);
                v[j] = (short)f2bf(fsilu(cv));
            }
            *reinterpret_cast<short8*>(Xs + c * 16) = v;
            *reinterpret_cast<short8*>(ubf + (size_t)m * DINNER + d0) = v;
        }
        __syncthreads();
        #pragma unroll
        for (int ks = 0; ks < 2; ++ks) {
            short8 bfr = *reinterpret_cast<short8*>(Xs + (w * 16 + lr) * 128 + ks * 64 + g * 16);
            #pragma unroll
            for (int aj = 0; aj < 3; ++aj) {
                short8 a = *reinterpret_cast<short8*>(Ws + (aj * 16 + lr) * 128 + ks * 64 + g * 16);
                acc[aj] = __builtin_amdgcn_mfma_f32_16x16x32_bf16(a, bfr, acc[aj], 0, 0, 0);
            }
        }
    }
    int mc = m0 + w * 16 + lr;
    #pragma unroll
    for (int aj = 0; aj < 3; ++aj)
        *reinterpret_cast<f32x4*>(dbc + (size_t)mc * 48 + aj * 16 + g * 4) = acc[aj];
}

// ---------------- K5: scan, dbc staged in LDS (no scalar-load stalls) -----------
__global__ __launch_bounds__(256) void k5_scan(const unsigned int* __restrict__ ubf2,
                                               const unsigned int* __restrict__ gbf2,
                                               const float* __restrict__ dbc,
                                               const float2* __restrict__ scanc,
                                               const float* __restrict__ w_dt,
                                               const float* __restrict__ b_dt,
                                               const float* __restrict__ A_log,
                                               const float* __restrict__ Dp,
                                               unsigned int* __restrict__ ybf2) {
    __shared__ float sdbc[NSAMP][48];     // 3 KB: all 16 steps' rows for this p
    int p = blockIdx.x, t = threadIdx.x;
    if (t < 192) {                        // 768 floats = 192 float4, 16B-aligned
        int fl = 4 * t;
        int row = fl / 48, col = fl % 48;
        *reinterpret_cast<float4*>(&sdbc[row][col]) =
            *reinterpret_cast<const float4*>(dbc + (size_t)((row << 10) + p) * 48 + col);
    }
    int d0 = 2 * t, d1 = d0 + 1;
    float2 s0c = scanc[d0], s1c = scanc[d1];
    float c00 = s0c.x, c01 = s1c.x;
    bool geo = (s0c.y > 0.5f) && (s1c.y > 0.5f);
    float2 Dv = *reinterpret_cast<const float2*>(Dp + d0);
    float2 bdt = *reinterpret_cast<const float2*>(b_dt + d0);
    float wdt0[16], wdt1[16];
    #pragma unroll
    for (int r = 0; r < 16; ++r) {
        float2 wv = *reinterpret_cast<const float2*>(w_dt + r * DINNER + d0);
        wdt0[r] = wv.x; wdt1[r] = wv.y;
    }
    float h0[16], h1[16];
    #pragma unroll
    for (int n = 0; n < 16; ++n) { h0[n] = 0.f; h1[n] = 0.f; }
    unsigned int base = p * 256 + t;
    __syncthreads();

    unsigned int uA = ubf2[base], gA = gbf2[base];
    for (int s = 0; s < NSAMP; ++s) {
        unsigned int u = uA, gg = gA;
        if (s < NSAMP - 1) {
            unsigned int o = ((unsigned int)(s + 1) << 18) + base;
            uA = ubf2[o]; gA = gbf2[o];
        }
        // delta projection from LDS (uniform float4 reads)
        float dp0 = bdt.x, dp1 = bdt.y;
        #pragma unroll
        for (int q = 0; q < 4; ++q) {
            float4 cv = *reinterpret_cast<const float4*>(&sdbc[s][q * 4]);
            dp0 += cv.x * wdt0[q*4] + cv.y * wdt0[q*4+1] + cv.z * wdt0[q*4+2] + cv.w * wdt0[q*4+3];
            dp1 += cv.x * wdt1[q*4] + cv.y * wdt1[q*4+1] + cv.z * wdt1[q*4+2] + cv.w * wdt1[q*4+3];
        }
        float dl0 = (dp0 > 20.f) ? dp0 : __logf(1.f + __expf(dp0));
        float dl1 = (dp1 > 20.f) ? dp1 : __logf(1.f + __expf(dp1));
        float u0, u1, g0, g1;
        unpk(u, u0, u1); unpk(gg, g0, g1);
        float du0 = dl0 * u0, du1 = dl1 * u1;
        float yv0 = 0.f, yv1 = 0.f;
        if (geo) {
            float r0 = exp2f(dl0 * c00), r1 = exp2f(dl1 * c01);
            float rr0 = r0, rr1 = r1;
            #pragma unroll
            for (int q = 0; q < 4; ++q) {
                float4 B4 = *reinterpret_cast<const float4*>(&sdbc[s][16 + q * 4]);
                float4 C4 = *reinterpret_cast<const float4*>(&sdbc[s][32 + q * 4]);
                #pragma unroll
                for (int j = 0; j < 4; ++j) {
                    int n = q * 4 + j;
                    float Bn = (j == 0) ? B4.x : (j == 1) ? B4.y : (j == 2) ? B4.z : B4.w;
                    float Cn = (j == 0) ? C4.x : (j == 1) ? C4.y : (j == 2) ? C4.z : C4.w;
                    h0[n] = rr0 * h0[n] + du0 * Bn; yv0 += h0[n] * Cn; rr0 *= r0;
                    h1[n] = rr1 * h1[n] + du1 * Bn; yv1 += h1[n] * Cn; rr1 *= r1;
                }
            }
        } else {
            #pragma unroll
            for (int n = 0; n < 16; ++n) {
                float Bn = sdbc[s][16 + n], Cn = sdbc[s][32 + n];
                float An0 = -__expf(A_log[d0 * 16 + n]);
                float An1 = -__expf(A_log[d1 * 16 + n]);
                h0[n] = __expf(dl0 * An0) * h0[n] + du0 * Bn; yv0 += h0[n] * Cn;
                h1[n] = __expf(dl1 * An1) * h1[n] + du1 * Bn; yv1 += h1[n] * Cn;
            }
        }
        unsigned int o = ((unsigned int)s << 18) + base;
        ybf2[o] = ((unsigned int)f2bf((yv1 + u1 * Dv.y) * g1) << 16) | f2bf((yv0 + u0 * Dv.x) * g0);
    }
}

// ---------------- K6: out = y @ w_out + x, gl16 staging, BK=64 ------------------
__global__ __launch_bounds__(256) void k6_mfma(const unsigned short* __restrict__ ybf,
                                               const unsigned short* __restrict__ w_outT,
                                               const float* __restrict__ feat,
                                               float* __restrict__ out) {
    __shared__ char As[128 * 128];
    __shared__ char Bs[128 * 128];
    int t = threadIdx.x;
    int m0 = blockIdx.x * 128;
    int cblk = blockIdx.y * 128;
    int s = m0 >> 10, p0 = m0 & 1023;
    int l = t & 63, w = t >> 6;
    int wm = w & 1, wn = w >> 1, g = l >> 4, lr = l & 15;

    f32x4 acc[4][4] = {};
    for (int k0 = 0; k0 < DINNER; k0 += 64) {
        if (k0) __syncthreads();
        #pragma unroll
        for (int q = 0; q < 4; ++q) {
            int chunk = q * 256 + t;
            int row = chunk >> 3, cb = chunk & 7;
            gl16(w_outT + (size_t)(cblk + row) * DINNER + k0 + cb * 8, As + chunk * 16);
            gl16(ybf    + (size_t)(m0 + row) * DINNER + k0 + cb * 8, Bs + chunk * 16);
        }
        __syncthreads();
        #pragma unroll
        for (int ks = 0; ks < 2; ++ks) {
            short8 a[4], b[4];
            #pragma unroll
            for (int mi = 0; mi < 4; ++mi)
                a[mi] = *reinterpret_cast<short8*>(As + (wm * 64 + mi * 16 + lr) * 128 + ks * 64 + g * 16);
            #pragma unroll
            for (int ni = 0; ni < 4; ++ni)
                b[ni] = *reinterpret_cast<short8*>(Bs + (wn * 64 + ni * 16 + lr) * 128 + ks * 64 + g * 16);
            #pragma unroll
            for (int mi = 0; mi < 4; ++mi)
                #pragma unroll
                for (int ni = 0; ni < 4; ++ni)
                    acc[mi][ni] = __builtin_amdgcn_mfma_f32_16x16x32_bf16(a[mi], b[ni], acc[mi][ni], 0, 0, 0);
        }
    }
    #pragma unroll
    for (int mi = 0; mi < 4; ++mi) {
        #pragma unroll
        for (int r = 0; r < 4; ++r) {
            int c = cblk + wm * 64 + mi * 16 + g * 4 + r;
            #pragma unroll
            for (int ni = 0; ni < 4; ++ni) {
                int p = p0 + wn * 64 + ni * 16 + lr;
                size_t idx = (size_t)s * (DMODEL * NPOS) + (size_t)c * NPOS + p;
                out[idx] = acc[mi][ni][r] + feat[idx];
            }
        }
    }
}

extern "C" void kernel_launch(void* const* d_in, const int* in_sizes, int n_in,
                              void* d_out, int out_size, void* d_ws, size_t ws_size,
                              hipStream_t stream) {
    const float* feature = (const float*)d_in[0];
    const float* norm_w  = (const float*)d_in[1];
    const float* w_in    = (const float*)d_in[2];
    const float* conv_w  = (const float*)d_in[3];
    const float* conv_b  = (const float*)d_in[4];
    const float* w_xproj = (const float*)d_in[5];
    const float* w_dt    = (const float*)d_in[6];
    const float* b_dt    = (const float*)d_in[7];
    const float* A_log   = (const float*)d_in[8];
    const float* Dp      = (const float*)d_in[9];
    const float* w_out   = (const float*)d_in[10];
    float* out = (float*)d_out;

    char* ws = (char*)d_ws;
    unsigned short* xnT    = (unsigned short*)(ws + 0);         // 8.4 MB
    unsigned short* xmbf   = (unsigned short*)(ws + 8388608);   // 16.8 MB
    unsigned short* gbf    = (unsigned short*)(ws + 25165824);  // 16.8 MB
    float*          dbc    = (float*)(ws + 41943040);           // 3.1 MB
    unsigned short* ubf    = (unsigned short*)(ws + 45088768);  // 16.8 MB
    unsigned short* ybf    = (unsigned short*)(ws + 61865984);  // 16.8 MB
    unsigned short* w_inT  = (unsigned short*)(ws + 78643200);  // 512 KB
    unsigned short* w_outT = (unsigned short*)(ws + 79167488);  // 256 KB
    unsigned short* wxT    = (unsigned short*)(ws + 79429632);  // 48 KB
    float2*         scanc  = (float2*)(ws + 79478784);          // 4 KB

    kprep2<<<449, 256, 0, stream>>>(feature, norm_w, w_in, w_out, w_xproj, A_log,
                                    xnT, w_inT, w_outT, wxT, scanc);
    k1_mfma<<<dim3(1024 / 128, MROWS / 256), 512, 0, stream>>>(xnT, w_inT, xmbf, gbf);
    k3_mfma<<<MROWS / 64, 256, 0, stream>>>(xmbf, conv_w, conv_b, wxT, dbc, ubf);
    k5_scan<<<NPOS, 256, 0, stream>>>((const unsigned int*)ubf, (const unsigned int*)gbf,
                                      dbc, scanc, w_dt, b_dt, A_log, Dp, (unsigned int*)ybf);
    k6_mfma<<<dim3(MROWS / 128, DMODEL / 128), 256, 0, stream>>>(ybf, w_outT, feature, out);
}